// Round 8
// baseline (240.331 us; speedup 1.0000x reference)
//
#include <hip/hip_runtime.h>
#include <stdint.h>

typedef unsigned int u32;
typedef unsigned long long u64;
typedef int i32x4 __attribute__((ext_vector_type(4)));

#define HW      3136     // 56*56
#define PADW    58
#define PADHW   3364     // 58*58

// d_ws layout
#define WT_OFF   0          // 128*1152 i8  (147456 B)  signed weights, [o][tap*128+c]
#define AP_OFF   147456     // 32*3364*128 i8 (13.78 MB) signed acts, channel-last padded
#define AP_IMG   (PADHW * 128)   // 430592 B per image

// prep grid split
#define NB_W     128      // weight-synthesis blocks (one per o)
#define NB_A     392      // apack interior: 32 b * 4 g * 784 quads / 256
#define NB_R     29       // ring-zero: 32 b * 228 ring px

// ---------------------------------------------------------------------------
// Prep: 3 block classes.
// [0,128):   weight synthesis (proven fmaf code) -> Wt[o][tap*128+c] as +1/-1 i8.
// [128,520): activation sign-pack -> Ap[b][pp][c] i8 channel-last (+1/-1).
//            x reads identical to the proven coalesced pattern.
// [520,549): zero the 58x58 ring (128 B per ring px) -> zero padding taps
//            contribute 0 to the i8 dot product, exactly like the f32 conv.
__global__ __launch_bounds__(256) void k_prep(
    const float* __restrict__ x,
    const float* __restrict__ M, const float* __restrict__ Z,
    const float* __restrict__ rv, char* __restrict__ ws)
{
  int t = threadIdx.x;
  if (blockIdx.x < NB_W) {
    // ---- weight synthesis for o = blockIdx.x ----
    __shared__ float sw[1152];      // [ch][tap]
    int o = blockIdx.x;
    float r0 = rv[0], r1 = rv[1], r2 = rv[2], r3 = rv[3], r4 = rv[4];
    const float4* M4 = (const float4*)M;
    const float4* Z4 = (const float4*)Z;
    float4* sw4 = (float4*)sw;

    for (int j = t; j < 288; j += 256) {
      float4 a = M4[o * 288 + j];
      float4 z;
      z = Z4[0 * 36864 + o * 288 + j];
      a.x = fmaf(r0, z.x, a.x); a.y = fmaf(r0, z.y, a.y);
      a.z = fmaf(r0, z.z, a.z); a.w = fmaf(r0, z.w, a.w);
      z = Z4[1 * 36864 + o * 288 + j];
      a.x = fmaf(r1, z.x, a.x); a.y = fmaf(r1, z.y, a.y);
      a.z = fmaf(r1, z.z, a.z); a.w = fmaf(r1, z.w, a.w);
      z = Z4[2 * 36864 + o * 288 + j];
      a.x = fmaf(r2, z.x, a.x); a.y = fmaf(r2, z.y, a.y);
      a.z = fmaf(r2, z.z, a.z); a.w = fmaf(r2, z.w, a.w);
      z = Z4[3 * 36864 + o * 288 + j];
      a.x = fmaf(r3, z.x, a.x); a.y = fmaf(r3, z.y, a.y);
      a.z = fmaf(r3, z.z, a.z); a.w = fmaf(r3, z.w, a.w);
      z = Z4[4 * 36864 + o * 288 + j];
      a.x = fmaf(r4, z.x, a.x); a.y = fmaf(r4, z.y, a.y);
      a.z = fmaf(r4, z.z, a.z); a.w = fmaf(r4, z.w, a.w);
      sw4[j] = a;
    }
    __syncthreads();

    // pack Wt[o][i], i = tap*128 + ch; sign(w)=sign(m+rv.z), rsqrt>0
    u32* wt32 = (u32*)(ws + WT_OFF);
    for (int j = t; j < 288; j += 256) {
      u32 wword = 0;
#pragma unroll
      for (int k2 = 0; k2 < 4; ++k2) {
        int i   = j * 4 + k2;         // 0..1151
        int tap = i >> 7;
        int ch  = i & 127;
        u32 bb = (sw[ch * 9 + tap] > 0.0f) ? 0x01u : 0xFFu;
        wword |= bb << (k2 * 8);
      }
      wt32[o * 288 + j] = wword;
    }
  } else if (blockIdx.x < NB_W + NB_A) {
    // ---- activation sign-pack, channel-last i8 ----
    char* Ap = ws + AP_OFF;
    int idx = (blockIdx.x - NB_W) * 256 + t;  // (b*4+g)*784 + q
    int bg  = idx / 784;
    int q   = idx - bg * 784;                 // pixel quad 0..783
    int b   = bg >> 2;
    int g   = bg & 3;
    int h   = q / 14;                         // 4 | 56 -> no row wrap in quad
    int w0  = (q - h * 14) * 4;

    const float4* X4 = (const float4*)x
        + ((size_t)b * 128 + g * 32) * (HW / 4) + q;
    u32 pk[4][8];
#pragma unroll
    for (int px = 0; px < 4; ++px)
#pragma unroll
      for (int wi = 0; wi < 8; ++wi) pk[px][wi] = 0;
#pragma unroll
    for (int c = 0; c < 32; ++c) {
      float4 f = X4[(size_t)c * (HW / 4)];
      int wi = c >> 2, sh = (c & 3) * 8;
      u32 b0 = f.x > 0.0f ? 0x01u : 0xFFu;
      u32 b1 = f.y > 0.0f ? 0x01u : 0xFFu;
      u32 b2 = f.z > 0.0f ? 0x01u : 0xFFu;
      u32 b3 = f.w > 0.0f ? 0x01u : 0xFFu;
      pk[0][wi] |= b0 << sh;
      pk[1][wi] |= b1 << sh;
      pk[2][wi] |= b2 << sh;
      pk[3][wi] |= b3 << sh;
    }
    // store: px (h+1, w0+1+px) channel bytes g*32..g*32+31
    size_t pbase = ((size_t)b * PADHW + (h + 1) * PADW + (w0 + 1)) * 128 + g * 32;
#pragma unroll
    for (int px = 0; px < 4; ++px) {
      uint4 v0 = make_uint4(pk[px][0], pk[px][1], pk[px][2], pk[px][3]);
      uint4 v1 = make_uint4(pk[px][4], pk[px][5], pk[px][6], pk[px][7]);
      *(uint4*)(Ap + pbase + (size_t)px * 128)      = v0;
      *(uint4*)(Ap + pbase + (size_t)px * 128 + 16) = v1;
    }
  } else {
    // ---- ring zero (128 B per ring pixel) ----
    char* Ap = ws + AP_OFF;
    int e = (blockIdx.x - NB_W - NB_A) * 256 + t;
    if (e >= 32 * 228) return;
    int b  = e / 228;
    int r  = e - b * 228;
    int pp;
    if      (r < 58)  pp = r;                       // top row
    else if (r < 116) pp = 57 * PADW + (r - 58);    // bottom row
    else {                                          // sides
      int s = r - 116;
      pp = (1 + (s >> 1)) * PADW + ((s & 1) ? 57 : 0);
    }
    char* p = Ap + ((size_t)b * PADHW + pp) * 128;
    uint4 z = make_uint4(0, 0, 0, 0);
#pragma unroll
    for (int k = 0; k < 8; ++k) *(uint4*)(p + k * 16) = z;
  }
}

// ---------------------------------------------------------------------------
// i8 MFMA conv-as-GEMM: D[o][px] = sum_k Wt[o][k] * Ap[px][k], K = 1152.
// Block = (image b, 2-row band) = 112 px (= 7 x 16 exactly) x 128 o.
// 8 waves x 512 thr: wave = one 16-o M-tile x 7 px N-tiles.
// acc = 7 x i32x4 = 28 VGPRs -> fits the ~64-reg default budget (rounds
// 1-5 lesson: never exceed what the allocator actually gives).
// Fragments (standard CDNA mapping, C/D verified dtype-independent):
//   A (weights): row = l&15 (o), k = (l>>4)*16 + j  -> 16B contig in Wt
//   B (acts):    col = l&15 (px), same k            -> 16B contig in Ap
//   D: row=(l>>4)*4+reg = o, col=l&15 = px -> stores are 16-lane px-contig.
// No LDS, no barriers; B-frags identical across waves -> L1-hot; weights
// L2-hot (147 KB). Zero ring makes border taps contribute 0 => epilogue
// is exactly out = (float)acc * alpha[o]. Matrix-pipe floor ~7.5 us.
__global__ __launch_bounds__(512) void k_mm(
    const char* __restrict__ ws, const float* __restrict__ Alpha,
    float* __restrict__ out)
{
  const char* Wt = ws + WT_OFF;
  const char* Ap = ws + AP_OFF;

  int t   = threadIdx.x;
  int wv  = t >> 6;            // wave 0..7 -> o-tile
  int l   = t & 63;
  int l15 = l & 15;
  int lk  = (l >> 4) * 16;     // k-group byte offset
  int o0  = wv * 16;

  int blk = blockIdx.x;        // 0..895
  int b   = blk / 28;
  int rb  = blk - b * 28;
  int h0  = rb * 2;

  const char* apb = Ap + (size_t)b * AP_IMG;

  // per-lane padded-pixel base for each px tile (px = n*16 + l15 < 112)
  int pp0[7];
#pragma unroll
  for (int n = 0; n < 7; ++n) {
    int px = n * 16 + l15;
    int r  = (px >= 56) ? 1 : 0;
    pp0[n] = (h0 + r) * PADW + (px - r * 56);
  }

  i32x4 acc[7];
#pragma unroll
  for (int n = 0; n < 7; ++n) acc[n] = (i32x4){0, 0, 0, 0};

  const char* wr = Wt + (size_t)(o0 + l15) * 1152 + lk;

#pragma unroll
  for (int tap = 0; tap < 9; ++tap) {
    const int dh = tap / 3, dw = tap - (tap / 3) * 3;
    const int sh = dh * PADW + dw;
#pragma unroll
    for (int kk = 0; kk < 2; ++kk) {
      i32x4 af = *(const i32x4*)(wr + tap * 128 + kk * 64);
#pragma unroll
      for (int n = 0; n < 7; ++n) {
        i32x4 bf = *(const i32x4*)(apb + (size_t)(pp0[n] + sh) * 128 + kk * 64 + lk);
        acc[n] = __builtin_amdgcn_mfma_i32_16x16x64_i8(af, bf, acc[n], 0, 0, 0);
      }
    }
  }

  // epilogue: out[b][o][h0*56 + px] = acc * alpha[o]
  // reg j -> o = o0 + (l>>4)*4 + j ; alpha contiguous float4 per lane
  float4 al = *(const float4*)(Alpha + o0 + (l >> 4) * 4);
  float* ob = out + ((size_t)b * 128 + o0 + (l >> 4) * 4) * HW + h0 * 56;
#pragma unroll
  for (int n = 0; n < 7; ++n) {
    int px = n * 16 + l15;
    float* op = ob + px;
    __builtin_nontemporal_store((float)acc[n].x * al.x, op);
    __builtin_nontemporal_store((float)acc[n].y * al.y, op + HW);
    __builtin_nontemporal_store((float)acc[n].z * al.z, op + 2 * HW);
    __builtin_nontemporal_store((float)acc[n].w * al.w, op + 3 * HW);
  }
}

// ---------------------------------------------------------------------------
extern "C" void kernel_launch(void* const* d_in, const int* in_sizes, int n_in,
                              void* d_out, int out_size, void* d_ws, size_t ws_size,
                              hipStream_t stream)
{
  const float* x     = (const float*)d_in[0];
  const float* Alpha = (const float*)d_in[1];
  const float* M     = (const float*)d_in[2];
  const float* Z     = (const float*)d_in[3];
  const float* rv    = (const float*)d_in[4];
  float* out         = (float*)d_out;
  char*  ws          = (char*)d_ws;

  k_prep<<<NB_W + NB_A + NB_R, 256, 0, stream>>>(x, M, Z, rv, ws);
  k_mm<<<32 * 28, 512, 0, stream>>>(ws, Alpha, out);
}

// Round 9
// 159.298 us; speedup vs baseline: 1.5087x; 1.5087x over previous
//
#include <hip/hip_runtime.h>
#include <stdint.h>

typedef unsigned int u32;
typedef unsigned long long u64;
typedef int i32x4 __attribute__((ext_vector_type(4)));

#define HW      3136     // 56*56
#define PADW    58
#define PADHW   3364     // 58*58

// d_ws layout
#define WT_OFF   0          // 128*1152 i8  (147456 B)  signed weights, [o][tap*128+c]
#define AP_OFF   147456     // 32*3364*128 i8 (13.78 MB) signed acts, channel-last padded
#define AP_IMG   (PADHW * 128)   // 430592 B per image

// prep grid split
#define NB_W     128      // weight-synthesis blocks (one per o)
#define NB_A     392      // apack interior: 32 b * 4 g * 784 quads / 256
#define NB_R     29       // ring-zero: 32 b * 228 ring px

// LDS band panel: 4 padded rows x 58 px x 128 B (contiguous span of Ap)
#define PANEL_B  (4 * PADW * 128)           // 29696
#define PANEL_U4 (PANEL_B / 16)             // 1856
// XOR swizzle: spread the 128B-per-pixel blocks across 16B slots.
// Involution (bits 4-6 ^= bits 7-9; bits 7-9 untouched) -> apply on both
// write and read (both-sides-or-neither rule).
__device__ __forceinline__ int swz(int byte_off) {
  return byte_off ^ (((byte_off >> 7) & 7) << 4);
}

// ---------------------------------------------------------------------------
// Prep: 3 block classes (round-8 proven: absmax 0.0).
__global__ __launch_bounds__(256) void k_prep(
    const float* __restrict__ x,
    const float* __restrict__ M, const float* __restrict__ Z,
    const float* __restrict__ rv, char* __restrict__ ws)
{
  int t = threadIdx.x;
  if (blockIdx.x < NB_W) {
    // ---- weight synthesis for o = blockIdx.x ----
    __shared__ float sw[1152];      // [ch][tap]
    int o = blockIdx.x;
    float r0 = rv[0], r1 = rv[1], r2 = rv[2], r3 = rv[3], r4 = rv[4];
    const float4* M4 = (const float4*)M;
    const float4* Z4 = (const float4*)Z;
    float4* sw4 = (float4*)sw;

    for (int j = t; j < 288; j += 256) {
      float4 a = M4[o * 288 + j];
      float4 z;
      z = Z4[0 * 36864 + o * 288 + j];
      a.x = fmaf(r0, z.x, a.x); a.y = fmaf(r0, z.y, a.y);
      a.z = fmaf(r0, z.z, a.z); a.w = fmaf(r0, z.w, a.w);
      z = Z4[1 * 36864 + o * 288 + j];
      a.x = fmaf(r1, z.x, a.x); a.y = fmaf(r1, z.y, a.y);
      a.z = fmaf(r1, z.z, a.z); a.w = fmaf(r1, z.w, a.w);
      z = Z4[2 * 36864 + o * 288 + j];
      a.x = fmaf(r2, z.x, a.x); a.y = fmaf(r2, z.y, a.y);
      a.z = fmaf(r2, z.z, a.z); a.w = fmaf(r2, z.w, a.w);
      z = Z4[3 * 36864 + o * 288 + j];
      a.x = fmaf(r3, z.x, a.x); a.y = fmaf(r3, z.y, a.y);
      a.z = fmaf(r3, z.z, a.z); a.w = fmaf(r3, z.w, a.w);
      z = Z4[4 * 36864 + o * 288 + j];
      a.x = fmaf(r4, z.x, a.x); a.y = fmaf(r4, z.y, a.y);
      a.z = fmaf(r4, z.z, a.z); a.w = fmaf(r4, z.w, a.w);
      sw4[j] = a;
    }
    __syncthreads();

    // pack Wt[o][i], i = tap*128 + ch; sign(w)=sign(m+rv.z), rsqrt>0
    u32* wt32 = (u32*)(ws + WT_OFF);
    for (int j = t; j < 288; j += 256) {
      u32 wword = 0;
#pragma unroll
      for (int k2 = 0; k2 < 4; ++k2) {
        int i   = j * 4 + k2;         // 0..1151
        int tap = i >> 7;
        int ch  = i & 127;
        u32 bb = (sw[ch * 9 + tap] > 0.0f) ? 0x01u : 0xFFu;
        wword |= bb << (k2 * 8);
      }
      wt32[o * 288 + j] = wword;
    }
  } else if (blockIdx.x < NB_W + NB_A) {
    // ---- activation sign-pack, channel-last i8 ----
    char* Ap = ws + AP_OFF;
    int idx = (blockIdx.x - NB_W) * 256 + t;  // (b*4+g)*784 + q
    int bg  = idx / 784;
    int q   = idx - bg * 784;                 // pixel quad 0..783
    int b   = bg >> 2;
    int g   = bg & 3;
    int h   = q / 14;                         // 4 | 56 -> no row wrap in quad
    int w0  = (q - h * 14) * 4;

    const float4* X4 = (const float4*)x
        + ((size_t)b * 128 + g * 32) * (HW / 4) + q;
    u32 pk[4][8];
#pragma unroll
    for (int px = 0; px < 4; ++px)
#pragma unroll
      for (int wi = 0; wi < 8; ++wi) pk[px][wi] = 0;
#pragma unroll
    for (int c = 0; c < 32; ++c) {
      float4 f = X4[(size_t)c * (HW / 4)];
      int wi = c >> 2, sh = (c & 3) * 8;
      u32 b0 = f.x > 0.0f ? 0x01u : 0xFFu;
      u32 b1 = f.y > 0.0f ? 0x01u : 0xFFu;
      u32 b2 = f.z > 0.0f ? 0x01u : 0xFFu;
      u32 b3 = f.w > 0.0f ? 0x01u : 0xFFu;
      pk[0][wi] |= b0 << sh;
      pk[1][wi] |= b1 << sh;
      pk[2][wi] |= b2 << sh;
      pk[3][wi] |= b3 << sh;
    }
    // store: px (h+1, w0+1+px) channel bytes g*32..g*32+31
    size_t pbase = ((size_t)b * PADHW + (h + 1) * PADW + (w0 + 1)) * 128 + g * 32;
#pragma unroll
    for (int px = 0; px < 4; ++px) {
      uint4 v0 = make_uint4(pk[px][0], pk[px][1], pk[px][2], pk[px][3]);
      uint4 v1 = make_uint4(pk[px][4], pk[px][5], pk[px][6], pk[px][7]);
      *(uint4*)(Ap + pbase + (size_t)px * 128)      = v0;
      *(uint4*)(Ap + pbase + (size_t)px * 128 + 16) = v1;
    }
  } else {
    // ---- ring zero (128 B per ring pixel) ----
    char* Ap = ws + AP_OFF;
    int e = (blockIdx.x - NB_W - NB_A) * 256 + t;
    if (e >= 32 * 228) return;
    int b  = e / 228;
    int r  = e - b * 228;
    int pp;
    if      (r < 58)  pp = r;                       // top row
    else if (r < 116) pp = 57 * PADW + (r - 58);    // bottom row
    else {                                          // sides
      int s = r - 116;
      pp = (1 + (s >> 1)) * PADW + ((s & 1) ? 57 : 0);
    }
    char* p = Ap + ((size_t)b * PADHW + pp) * 128;
    uint4 z = make_uint4(0, 0, 0, 0);
#pragma unroll
    for (int k = 0; k < 8; ++k) *(uint4*)(p + k * 16) = z;
  }
}

// ---------------------------------------------------------------------------
// i8 MFMA conv-as-GEMM, LDS-fed.
// Round-8 diagnosis: MfmaUtil 4% = VALUBusy 4% -> latency-bound; 126
// dependent scattered global B-loads/wave serialized at L2 latency
// (VGPR=44 -> ~2 in flight). Fix: one bulk LDS stage per block (the
// band's B-panel is a CONTIGUOUS 29696 B span of Ap -> linear coalesced
// copy, deep vmcnt), then B-frags come from ds_read_b128.
// XOR swizzle (bits4-6 ^= bits7-9) on write AND read kills the
// px-stride-128B bank conflict (16 lanes -> 8 slots, 2-way = free).
// Block = 256 thr / 4 waves = (image, 2-row band) x 64 o; wave =
// (wo: 32 o) x (wp: 4 or 3 px-tiles); each B-frag feeds 2 MFMAs (o and
// o+16) -> LDS read traffic 452 MB ~ 6.6 us, overlapping the 7.5 us
// MFMA floor. Grid 1792 (o-half fastest: block pairs share the panel in
// L2); LDS 29.7 KB -> 5 blocks/CU resident, 20 waves/CU.
// Fragment mapping unchanged from round 8 (absmax 0.0 verified).
__global__ __launch_bounds__(256) void k_mm(
    const char* __restrict__ ws, const float* __restrict__ Alpha,
    float* __restrict__ out)
{
  __shared__ char sB[PANEL_B];     // 29696 B, swizzled

  const char* Wt = ws + WT_OFF;
  const char* Ap = ws + AP_OFF;

  int t   = threadIdx.x;
  int blk = blockIdx.x;            // 0..1791 : ((b*28 + rb)*2 + oh)
  int oh  = blk & 1;
  int bb  = blk >> 1;
  int b   = bb / 28;
  int rb  = bb - b * 28;
  int h0  = rb * 2;

  // ---- stage the band panel: padded rows h0..h0+3, contiguous in Ap ----
  {
    const char* src = Ap + (size_t)b * AP_IMG + (size_t)h0 * PADW * 128;
    for (int j = t; j < PANEL_U4; j += 256) {
      uint4 v = *(const uint4*)(src + (size_t)j * 16);
      *(uint4*)(sB + swz(j * 16)) = v;
    }
  }
  __syncthreads();

  int wv  = t >> 6;                // 0..3
  int wo  = wv & 1;                // o sub-tile pair
  int wp  = wv >> 1;               // px-tile half
  int l   = t & 63;
  int l15 = l & 15;
  int lk  = (l >> 4) * 16;         // k-group byte offset
  int o0  = oh * 64 + wo * 32;     // this wave's 32-o base

  int nt0 = wp * 4;                // first px tile
  int ntn = wp ? 3 : 4;            // tiles this wave

  // per-tile per-lane LDS base (pre-swizzle byte offset)
  int pb[4];
#pragma unroll
  for (int i = 0; i < 4; ++i) {
    int px = (nt0 + i) * 16 + l15;       // 0..111
    int r  = (px >= 56) ? 1 : 0;
    pb[i] = ((r) * PADW + (px - r * 56)) * 128 + lk;
  }

  i32x4 acc[4][2];
#pragma unroll
  for (int i = 0; i < 4; ++i) {
    acc[i][0] = (i32x4){0, 0, 0, 0};
    acc[i][1] = (i32x4){0, 0, 0, 0};
  }

  const char* wr = Wt + (size_t)(o0 + l15) * 1152 + lk;

#pragma unroll
  for (int tap = 0; tap < 9; ++tap) {
    const int dh = tap / 3, dw = tap - (tap / 3) * 3;
    const int sh = (dh * PADW + dw) * 128;
#pragma unroll
    for (int kk = 0; kk < 2; ++kk) {
      i32x4 af0 = *(const i32x4*)(wr + tap * 128 + kk * 64);
      i32x4 af1 = *(const i32x4*)(wr + 16 * 1152 + tap * 128 + kk * 64);
#pragma unroll
      for (int i = 0; i < 4; ++i) {
        if (i < ntn) {
          i32x4 bf = *(const i32x4*)(sB + swz(pb[i] + sh + kk * 64));
          acc[i][0] = __builtin_amdgcn_mfma_i32_16x16x64_i8(af0, bf, acc[i][0], 0, 0, 0);
          acc[i][1] = __builtin_amdgcn_mfma_i32_16x16x64_i8(af1, bf, acc[i][1], 0, 0, 0);
        }
      }
    }
  }

  // ---- epilogue: out[b][o][h0*56 + px] = acc * alpha[o] ----
  // D mapping (round-8 verified): col = l15 = px-in-tile, row = (l>>4)*4+j = o
#pragma unroll
  for (int s = 0; s < 2; ++s) {
    float4 al = *(const float4*)(Alpha + o0 + s * 16 + (l >> 4) * 4);
    float* ob = out + ((size_t)b * 128 + o0 + s * 16 + (l >> 4) * 4) * HW
              + h0 * 56;
#pragma unroll
    for (int i = 0; i < 4; ++i) {
      if (i < ntn) {
        int px = (nt0 + i) * 16 + l15;
        float* op = ob + px;
        __builtin_nontemporal_store((float)acc[i][s].x * al.x, op);
        __builtin_nontemporal_store((float)acc[i][s].y * al.y, op + HW);
        __builtin_nontemporal_store((float)acc[i][s].z * al.z, op + 2 * HW);
        __builtin_nontemporal_store((float)acc[i][s].w * al.w, op + 3 * HW);
      }
    }
  }
}

// ---------------------------------------------------------------------------
extern "C" void kernel_launch(void* const* d_in, const int* in_sizes, int n_in,
                              void* d_out, int out_size, void* d_ws, size_t ws_size,
                              hipStream_t stream)
{
  const float* x     = (const float*)d_in[0];
  const float* Alpha = (const float*)d_in[1];
  const float* M     = (const float*)d_in[2];
  const float* Z     = (const float*)d_in[3];
  const float* rv    = (const float*)d_in[4];
  float* out         = (float*)d_out;
  char*  ws          = (char*)d_ws;

  k_prep<<<NB_W + NB_A + NB_R, 256, 0, stream>>>(x, M, Z, rv, ws);
  k_mm<<<32 * 28 * 2, 256, 0, stream>>>(ws, Alpha, out);
}